// Round 3
// baseline (86.759 us; speedup 1.0000x reference)
//
#include <hip/hip_runtime.h>
#include <hip/hip_bf16.h>

#define N_VOX 100000
#define C_IN  32
#define C_OUT 64
#define KOFF  27
#define NB_CONV 1563   // ceil(100000/64), 4 waves/block, 16 voxels/wave

typedef __attribute__((ext_vector_type(8))) short bf16x8_t;
typedef __attribute__((ext_vector_type(4))) float f32x4_t;

__device__ __forceinline__ short f2bf(float f) {
    __hip_bfloat16 h = __float2bfloat16(f);
    return __builtin_bit_cast(short, h);
}

// Wt[k][d][c] = bf16(W[k][c][d])  -- B-fragments contiguous 16B per lane
__global__ void prep_w_kernel(const float* __restrict__ W,
                              unsigned short* __restrict__ Wt) {
    int i = blockIdx.x * 256 + threadIdx.x;
    if (i >= KOFF * C_OUT * C_IN) return;
    int c = i & 31;
    int d = (i >> 5) & 63;
    int k = i >> 11;
    Wt[i] = (unsigned short)f2bf(W[k * (C_IN * C_OUT) + c * C_OUT + d]);
}

// features f32 -> bf16, plus an all-zero row at index N_VOX
__global__ void prep_feat_kernel(const float* __restrict__ feat,
                                 unsigned short* __restrict__ fb) {
    int t = blockIdx.x * 256 + threadIdx.x;        // one thread per 8 elems
    const int total8 = ((N_VOX + 1) * C_IN) / 8;   // 400004
    if (t >= total8) return;
    int e = t * 8;
    bf16x8_t o;
    if (e < N_VOX * C_IN) {
        const f32x4_t* fp = (const f32x4_t*)(feat + e);
        f32x4_t f0 = fp[0], f1 = fp[1];
        o[0] = f2bf(f0[0]); o[1] = f2bf(f0[1]); o[2] = f2bf(f0[2]); o[3] = f2bf(f0[3]);
        o[4] = f2bf(f1[0]); o[5] = f2bf(f1[1]); o[6] = f2bf(f1[2]); o[7] = f2bf(f1[3]);
    } else {
        o = (bf16x8_t)(short)0;
    }
    *(bf16x8_t*)(fb + e) = o;
}

template <bool BF>
__global__ __launch_bounds__(256, 8) void conv_kernel(
    const float* __restrict__ feat_f32,
    const unsigned short* __restrict__ feat_bf,
    const int* __restrict__ nidx,
    const unsigned short* __restrict__ Wt,
    float* __restrict__ out, float* __restrict__ partials)
{
    __shared__ float lsum[4][C_OUT];
    __shared__ float lsq[4][C_OUT];

    const int wid  = threadIdx.x >> 6;
    const int lane = threadIdx.x & 63;
    const int colr = lane & 15;   // A row (voxel) / C col (channel)
    const int kch  = lane >> 4;   // k-chunk 0..3
    const int c0   = kch * 8;     // input-channel start of fragment
    const int base = blockIdx.x * 64 + wid * 16;
    const int vox  = base + colr;
    const bool valid = (vox < N_VOX);
    const int force = valid ? 0 : -1;            // idx|force = -1 for pad rows
    const int* nrow = nidx + (valid ? vox : 0) * KOFF;

    f32x4_t acc[4];
    #pragma unroll
    for (int t = 0; t < 4; ++t) acc[t] = (f32x4_t)0.0f;

    auto gather = [&](int idx) -> bf16x8_t {
        bf16x8_t a;
        if constexpr (BF) {
            int s = (idx < 0) ? N_VOX : idx;     // zero row for invalid
            a = *(const bf16x8_t*)(feat_bf + (s << 5) + c0);
        } else {
            a = (bf16x8_t)(short)0;
            if (idx >= 0) {
                const f32x4_t* fp = (const f32x4_t*)(feat_f32 + (idx << 5) + c0);
                f32x4_t f0 = fp[0], f1 = fp[1];
                a[0] = f2bf(f0[0]); a[1] = f2bf(f0[1]);
                a[2] = f2bf(f0[2]); a[3] = f2bf(f0[3]);
                a[4] = f2bf(f1[0]); a[5] = f2bf(f1[1]);
                a[6] = f2bf(f1[2]); a[7] = f2bf(f1[3]);
            }
        }
        return a;
    };

    int idx0 = nrow[0] | force;
    bf16x8_t a_cur = gather(idx0);
    #pragma unroll 3
    for (int k = 0; k < KOFF; ++k) {
        bf16x8_t a_nxt;
        if (k < KOFF - 1) {
            int idn = nrow[k + 1] | force;
            a_nxt = gather(idn);                 // in flight during MFMAs below
        } else {
            a_nxt = (bf16x8_t)(short)0;
        }
        const unsigned short* wk = Wt + k * (C_OUT * C_IN);
        #pragma unroll
        for (int t = 0; t < 4; ++t) {
            bf16x8_t b = *(const bf16x8_t*)(wk + (t * 16 + colr) * C_IN + c0);
            acc[t] = __builtin_amdgcn_mfma_f32_16x16x32_bf16(a_cur, b, acc[t], 0, 0, 0);
        }
        a_cur = a_nxt;
    }

    // epilogue: C/D layout col = lane&15, row = (lane>>4)*4 + i
    float psum[4], psq[4];
    #pragma unroll
    for (int t = 0; t < 4; ++t) { psum[t] = 0.f; psq[t] = 0.f; }

    #pragma unroll
    for (int t = 0; t < 4; ++t) {
        #pragma unroll
        for (int i = 0; i < 4; ++i) {
            int v = base + kch * 4 + i;
            float x = acc[t][i];
            if (v < N_VOX) out[v * C_OUT + t * 16 + colr] = x;
            psum[t] += x;           // pad rows are exactly 0
            psq[t]  += x * x;
        }
    }

    #pragma unroll
    for (int t = 0; t < 4; ++t) {
        psum[t] += __shfl_xor(psum[t], 16);
        psum[t] += __shfl_xor(psum[t], 32);
        psq[t]  += __shfl_xor(psq[t], 16);
        psq[t]  += __shfl_xor(psq[t], 32);
    }
    if (lane < 16) {
        #pragma unroll
        for (int t = 0; t < 4; ++t) {
            lsum[wid][t * 16 + lane] = psum[t];
            lsq[wid][t * 16 + lane]  = psq[t];
        }
    }
    __syncthreads();
    // channel-major partials: rows 0..63 = sum[c], rows 64..127 = sumsq[c]
    if (threadIdx.x < 128) {
        int c = threadIdx.x & 63;
        float s;
        if (threadIdx.x < 64)
            s = lsum[0][c] + lsum[1][c] + lsum[2][c] + lsum[3][c];
        else
            s = lsq[0][c] + lsq[1][c] + lsq[2][c] + lsq[3][c];
        partials[threadIdx.x * NB_CONV + blockIdx.x] = s;
    }
}

// one block per output channel: coalesced reduction over NB_CONV partials
__global__ __launch_bounds__(256) void stats_kernel(
    const float* __restrict__ partials,
    const float* __restrict__ gamma, const float* __restrict__ beta,
    float* __restrict__ ss)
{
    __shared__ float bs[4], bq[4];
    const int c = blockIdx.x;
    const float* ps = partials + c * NB_CONV;
    const float* pq = partials + (64 + c) * NB_CONV;
    float s = 0.f, q = 0.f;
    for (int i = threadIdx.x; i < NB_CONV; i += 256) {
        s += ps[i];
        q += pq[i];
    }
    #pragma unroll
    for (int o = 1; o < 64; o <<= 1) {
        s += __shfl_xor(s, o);
        q += __shfl_xor(q, o);
    }
    int wid = threadIdx.x >> 6, lane = threadIdx.x & 63;
    if (lane == 0) { bs[wid] = s; bq[wid] = q; }
    __syncthreads();
    if (threadIdx.x == 0) {
        float S = bs[0] + bs[1] + bs[2] + bs[3];
        float Q = bq[0] + bq[1] + bq[2] + bq[3];
        float mean = S * (1.0f / N_VOX);
        float var  = Q * (1.0f / N_VOX) - mean * mean;
        float inv  = rsqrtf(var + 1e-5f);
        float sc   = gamma[c] * inv;
        ss[c]      = sc;
        ss[64 + c] = beta[c] - mean * sc;
    }
}

__global__ void bn_relu_kernel(float* __restrict__ out,
                               const float* __restrict__ ss) {
    int i = blockIdx.x * 256 + threadIdx.x;  // exactly N*64/4 threads
    f32x4_t v = ((f32x4_t*)out)[i];
    int d0 = (i * 4) & 63;
    f32x4_t sc = *(const f32x4_t*)(ss + d0);
    f32x4_t sh = *(const f32x4_t*)(ss + 64 + d0);
    #pragma unroll
    for (int j = 0; j < 4; ++j) v[j] = fmaxf(v[j] * sc[j] + sh[j], 0.f);
    ((f32x4_t*)out)[i] = v;
}

extern "C" void kernel_launch(void* const* d_in, const int* in_sizes, int n_in,
                              void* d_out, int out_size, void* d_ws, size_t ws_size,
                              hipStream_t stream) {
    const float* feat  = (const float*)d_in[0];
    const int*   nidx  = (const int*)d_in[1];
    const float* W     = (const float*)d_in[2];
    const float* gamma = (const float*)d_in[3];
    const float* beta  = (const float*)d_in[4];
    float* out = (float*)d_out;

    char* ws = (char*)d_ws;
    const size_t wt_bytes = KOFF * C_OUT * C_IN * 2;          // 110592
    const size_t fb_bytes = (size_t)(N_VOX + 1) * C_IN * 2;   // 6400064
    const size_t pt_bytes = 128 * NB_CONV * 4;                // 800256

    unsigned short* Wt = (unsigned short*)ws;
    const bool bf_ok = ws_size >= wt_bytes + fb_bytes + pt_bytes + 512;

    unsigned short* feat_bf;
    float* partials;
    if (bf_ok) {
        feat_bf  = (unsigned short*)(ws + wt_bytes);
        partials = (float*)(ws + wt_bytes + fb_bytes);
    } else {
        feat_bf  = nullptr;
        partials = (float*)(ws + wt_bytes);
    }
    float* ss = partials + 128 * NB_CONV;

    int wt_elems = KOFF * C_OUT * C_IN;
    prep_w_kernel<<<(wt_elems + 255) / 256, 256, 0, stream>>>(W, Wt);
    if (bf_ok) {
        int total8 = ((N_VOX + 1) * C_IN) / 8;
        prep_feat_kernel<<<(total8 + 255) / 256, 256, 0, stream>>>(feat, feat_bf);
        conv_kernel<true><<<NB_CONV, 256, 0, stream>>>(feat, feat_bf, nidx, Wt, out, partials);
    } else {
        conv_kernel<false><<<NB_CONV, 256, 0, stream>>>(feat, feat_bf, nidx, Wt, out, partials);
    }
    stats_kernel<<<C_OUT, 256, 0, stream>>>(partials, gamma, beta, ss);
    bn_relu_kernel<<<(N_VOX * C_OUT / 4 + 255) / 256, 256, 0, stream>>>(out, ss);
}

// Round 4
// 83.800 us; speedup vs baseline: 1.0353x; 1.0353x over previous
//
#include <hip/hip_runtime.h>
#include <hip/hip_bf16.h>

#define N_VOX 100000
#define C_IN  32
#define C_OUT 64
#define KOFF  27
#define NB_CONV 1563   // ceil(100000/64), 4 waves/block, 16 voxels/wave

typedef __attribute__((ext_vector_type(8))) short bf16x8_t;
typedef __attribute__((ext_vector_type(4))) float f32x4_t;

__device__ __forceinline__ short f2bf(float f) {
    __hip_bfloat16 h = __float2bfloat16(f);
    return __builtin_bit_cast(short, h);
}

// Wt[k][d][c] = bf16(W[k][c][d])  -- B-fragments contiguous 16B per lane
__global__ void prep_w_kernel(const float* __restrict__ W,
                              unsigned short* __restrict__ Wt) {
    int i = blockIdx.x * 256 + threadIdx.x;
    if (i >= KOFF * C_OUT * C_IN) return;
    int c = i & 31;
    int d = (i >> 5) & 63;
    int k = i >> 11;
    Wt[i] = (unsigned short)f2bf(W[k * (C_IN * C_OUT) + c * C_OUT + d]);
}

// features f32 -> bf16, plus an all-zero row at index N_VOX
__global__ void prep_feat_kernel(const float* __restrict__ feat,
                                 unsigned short* __restrict__ fb) {
    int t = blockIdx.x * 256 + threadIdx.x;        // one thread per 8 elems
    const int total8 = ((N_VOX + 1) * C_IN) / 8;   // 400004
    if (t >= total8) return;
    int e = t * 8;
    bf16x8_t o;
    if (e < N_VOX * C_IN) {
        const f32x4_t* fp = (const f32x4_t*)(feat + e);
        f32x4_t f0 = fp[0], f1 = fp[1];
        o[0] = f2bf(f0[0]); o[1] = f2bf(f0[1]); o[2] = f2bf(f0[2]); o[3] = f2bf(f0[3]);
        o[4] = f2bf(f1[0]); o[5] = f2bf(f1[1]); o[6] = f2bf(f1[2]); o[7] = f2bf(f1[3]);
    } else {
        o = (bf16x8_t)(short)0;
    }
    *(bf16x8_t*)(fb + e) = o;
}

template <bool BF>
__global__ __launch_bounds__(256, 2) void conv_kernel(
    const float* __restrict__ feat_f32,
    const unsigned short* __restrict__ feat_bf,
    const int* __restrict__ nidx,
    const unsigned short* __restrict__ Wt,
    float* __restrict__ out, float* __restrict__ partials)
{
    __shared__ float lsum[4][C_OUT];
    __shared__ float lsq[4][C_OUT];

    const int wid  = threadIdx.x >> 6;
    const int lane = threadIdx.x & 63;
    const int colr = lane & 15;   // A row (voxel) / C col (channel)
    const int kch  = lane >> 4;   // k-chunk 0..3
    const int c0   = kch * 8;     // input-channel start of fragment
    const int base = blockIdx.x * 64 + wid * 16;
    const int vox  = base + colr;
    const bool valid = (vox < N_VOX);
    const int force = valid ? 0 : -1;            // idx|force = -1 for pad rows
    const int* nrow = nidx + (valid ? vox : 0) * KOFF;

    f32x4_t acc[4];
    #pragma unroll
    for (int t = 0; t < 4; ++t) acc[t] = (f32x4_t)0.0f;

    if constexpr (BF) {
        // ---- deep-ILP path: all 27 gathers in flight before any MFMA ----
        int idxs[KOFF];
        #pragma unroll
        for (int k = 0; k < KOFF; ++k) idxs[k] = nrow[k] | force;

        bf16x8_t a[KOFF];
        #pragma unroll
        for (int k = 0; k < KOFF; ++k) {
            int s = (idxs[k] < 0) ? N_VOX : idxs[k];   // zero row if invalid
            a[k] = *(const bf16x8_t*)(feat_bf + (s << 5) + c0);
        }

        #pragma unroll
        for (int k = 0; k < KOFF; ++k) {
            const unsigned short* wk = Wt + k * (C_OUT * C_IN);
            #pragma unroll
            for (int t = 0; t < 4; ++t) {
                bf16x8_t b = *(const bf16x8_t*)(wk + (t * 16 + colr) * C_IN + c0);
                acc[t] = __builtin_amdgcn_mfma_f32_16x16x32_bf16(a[k], b, acc[t], 0, 0, 0);
            }
        }
    } else {
        // ---- fallback (ws too small): shallow-pipeline f32 path ----
        int idx = valid ? nrow[0] : -1;
        for (int k = 0; k < KOFF; ++k) {
            int idx_next = (k < KOFF - 1 && valid) ? nrow[k + 1] : -1;
            if (__any(idx >= 0)) {
                bf16x8_t a = (bf16x8_t)(short)0;
                if (idx >= 0) {
                    const f32x4_t* fp = (const f32x4_t*)(feat_f32 + (idx << 5) + c0);
                    f32x4_t f0 = fp[0], f1 = fp[1];
                    a[0] = f2bf(f0[0]); a[1] = f2bf(f0[1]);
                    a[2] = f2bf(f0[2]); a[3] = f2bf(f0[3]);
                    a[4] = f2bf(f1[0]); a[5] = f2bf(f1[1]);
                    a[6] = f2bf(f1[2]); a[7] = f2bf(f1[3]);
                }
                const unsigned short* wk = Wt + k * (C_OUT * C_IN);
                #pragma unroll
                for (int t = 0; t < 4; ++t) {
                    bf16x8_t b = *(const bf16x8_t*)(wk + (t * 16 + colr) * C_IN + c0);
                    acc[t] = __builtin_amdgcn_mfma_f32_16x16x32_bf16(a, b, acc[t], 0, 0, 0);
                }
            }
            idx = idx_next;
        }
    }

    // epilogue: C/D layout col = lane&15, row = (lane>>4)*4 + i
    float psum[4], psq[4];
    #pragma unroll
    for (int t = 0; t < 4; ++t) { psum[t] = 0.f; psq[t] = 0.f; }

    #pragma unroll
    for (int t = 0; t < 4; ++t) {
        #pragma unroll
        for (int i = 0; i < 4; ++i) {
            int v = base + kch * 4 + i;
            float x = acc[t][i];
            if (v < N_VOX) out[v * C_OUT + t * 16 + colr] = x;
            psum[t] += x;           // pad rows are exactly 0
            psq[t]  += x * x;
        }
    }

    #pragma unroll
    for (int t = 0; t < 4; ++t) {
        psum[t] += __shfl_xor(psum[t], 16);
        psum[t] += __shfl_xor(psum[t], 32);
        psq[t]  += __shfl_xor(psq[t], 16);
        psq[t]  += __shfl_xor(psq[t], 32);
    }
    if (lane < 16) {
        #pragma unroll
        for (int t = 0; t < 4; ++t) {
            lsum[wid][t * 16 + lane] = psum[t];
            lsq[wid][t * 16 + lane]  = psq[t];
        }
    }
    __syncthreads();
    // channel-major partials: rows 0..63 = sum[c], rows 64..127 = sumsq[c]
    if (threadIdx.x < 128) {
        int c = threadIdx.x & 63;
        float s;
        if (threadIdx.x < 64)
            s = lsum[0][c] + lsum[1][c] + lsum[2][c] + lsum[3][c];
        else
            s = lsq[0][c] + lsq[1][c] + lsq[2][c] + lsq[3][c];
        partials[threadIdx.x * NB_CONV + blockIdx.x] = s;
    }
}

// one block per output channel: coalesced reduction over NB_CONV partials
__global__ __launch_bounds__(256) void stats_kernel(
    const float* __restrict__ partials,
    const float* __restrict__ gamma, const float* __restrict__ beta,
    float* __restrict__ ss)
{
    __shared__ float bs[4], bq[4];
    const int c = blockIdx.x;
    const float* ps = partials + c * NB_CONV;
    const float* pq = partials + (64 + c) * NB_CONV;
    float s = 0.f, q = 0.f;
    for (int i = threadIdx.x; i < NB_CONV; i += 256) {
        s += ps[i];
        q += pq[i];
    }
    #pragma unroll
    for (int o = 1; o < 64; o <<= 1) {
        s += __shfl_xor(s, o);
        q += __shfl_xor(q, o);
    }
    int wid = threadIdx.x >> 6, lane = threadIdx.x & 63;
    if (lane == 0) { bs[wid] = s; bq[wid] = q; }
    __syncthreads();
    if (threadIdx.x == 0) {
        float S = bs[0] + bs[1] + bs[2] + bs[3];
        float Q = bq[0] + bq[1] + bq[2] + bq[3];
        float mean = S * (1.0f / N_VOX);
        float var  = Q * (1.0f / N_VOX) - mean * mean;
        float inv  = rsqrtf(var + 1e-5f);
        float sc   = gamma[c] * inv;
        ss[c]      = sc;
        ss[64 + c] = beta[c] - mean * sc;
    }
}

__global__ void bn_relu_kernel(float* __restrict__ out,
                               const float* __restrict__ ss) {
    int i = blockIdx.x * 256 + threadIdx.x;  // exactly N*64/4 threads
    f32x4_t v = ((f32x4_t*)out)[i];
    int d0 = (i * 4) & 63;
    f32x4_t sc = *(const f32x4_t*)(ss + d0);
    f32x4_t sh = *(const f32x4_t*)(ss + 64 + d0);
    #pragma unroll
    for (int j = 0; j < 4; ++j) v[j] = fmaxf(v[j] * sc[j] + sh[j], 0.f);
    ((f32x4_t*)out)[i] = v;
}

extern "C" void kernel_launch(void* const* d_in, const int* in_sizes, int n_in,
                              void* d_out, int out_size, void* d_ws, size_t ws_size,
                              hipStream_t stream) {
    const float* feat  = (const float*)d_in[0];
    const int*   nidx  = (const int*)d_in[1];
    const float* W     = (const float*)d_in[2];
    const float* gamma = (const float*)d_in[3];
    const float* beta  = (const float*)d_in[4];
    float* out = (float*)d_out;

    char* ws = (char*)d_ws;
    const size_t wt_bytes = KOFF * C_OUT * C_IN * 2;          // 110592
    const size_t fb_bytes = (size_t)(N_VOX + 1) * C_IN * 2;   // 6400064
    const size_t pt_bytes = 128 * NB_CONV * 4;                // 800256

    unsigned short* Wt = (unsigned short*)ws;
    const bool bf_ok = ws_size >= wt_bytes + fb_bytes + pt_bytes + 512;

    unsigned short* feat_bf;
    float* partials;
    if (bf_ok) {
        feat_bf  = (unsigned short*)(ws + wt_bytes);
        partials = (float*)(ws + wt_bytes + fb_bytes);
    } else {
        feat_bf  = nullptr;
        partials = (float*)(ws + wt_bytes);
    }
    float* ss = partials + 128 * NB_CONV;

    int wt_elems = KOFF * C_OUT * C_IN;
    prep_w_kernel<<<(wt_elems + 255) / 256, 256, 0, stream>>>(W, Wt);
    if (bf_ok) {
        int total8 = ((N_VOX + 1) * C_IN) / 8;
        prep_feat_kernel<<<(total8 + 255) / 256, 256, 0, stream>>>(feat, feat_bf);
        conv_kernel<true><<<NB_CONV, 256, 0, stream>>>(feat, feat_bf, nidx, Wt, out, partials);
    } else {
        conv_kernel<false><<<NB_CONV, 256, 0, stream>>>(feat, feat_bf, nidx, Wt, out, partials);
    }
    stats_kernel<<<C_OUT, 256, 0, stream>>>(partials, gamma, beta, ss);
    bn_relu_kernel<<<(N_VOX * C_OUT / 4 + 255) / 256, 256, 0, stream>>>(out, ss);
}

// Round 5
// 80.905 us; speedup vs baseline: 1.0724x; 1.0358x over previous
//
#include <hip/hip_runtime.h>
#include <hip/hip_bf16.h>

#define N_VOX 100000
#define C_IN  32
#define C_OUT 64
#define KOFF  27
#define NB_CONV 1563   // ceil(100000/64), 4 waves/block, 16 voxels/wave
#define WT_BLOCKS 216  // 27*64*32 / 256

typedef __attribute__((ext_vector_type(8))) short bf16x8_t;
typedef __attribute__((ext_vector_type(4))) float f32x4_t;

__device__ __forceinline__ short f2bf(float f) {
    __hip_bfloat16 h = __float2bfloat16(f);
    return __builtin_bit_cast(short, h);
}

// combined prep: blocks [0,216) transpose W -> Wt[k][d][c] bf16;
// blocks [216, ...) convert features f32 -> bf16 (+ zero row at N_VOX)
__global__ void prep_kernel(const float* __restrict__ W,
                            unsigned short* __restrict__ Wt,
                            const float* __restrict__ feat,
                            unsigned short* __restrict__ fb) {
    int bid = blockIdx.x;
    if (bid < WT_BLOCKS) {
        int i = bid * 256 + threadIdx.x;   // exactly 55296 threads
        int c = i & 31;
        int d = (i >> 5) & 63;
        int k = i >> 11;
        Wt[i] = (unsigned short)f2bf(W[k * (C_IN * C_OUT) + c * C_OUT + d]);
    } else {
        int t = (bid - WT_BLOCKS) * 256 + threadIdx.x;  // one thread per 8 elems
        const int total8 = ((N_VOX + 1) * C_IN) / 8;    // 400004
        if (t >= total8) return;
        int e = t * 8;
        bf16x8_t o;
        if (e < N_VOX * C_IN) {
            const f32x4_t* fp = (const f32x4_t*)(feat + e);
            f32x4_t f0 = fp[0], f1 = fp[1];
            o[0] = f2bf(f0[0]); o[1] = f2bf(f0[1]); o[2] = f2bf(f0[2]); o[3] = f2bf(f0[3]);
            o[4] = f2bf(f1[0]); o[5] = f2bf(f1[1]); o[6] = f2bf(f1[2]); o[7] = f2bf(f1[3]);
        } else {
            o = (bf16x8_t)(short)0;
        }
        *(bf16x8_t*)(fb + e) = o;
    }
}

// un-sinkable gather: KN independent 16B loads issued back-to-back
template <int K0, int KN>
__device__ __forceinline__ void gather_chunk(const unsigned short* __restrict__ feat_bf,
                                             const int* idxs, int c0, bf16x8_t* a) {
    #pragma unroll
    for (int j = 0; j < KN; ++j) {
        int idx = idxs[K0 + j];
        int s = (idx < 0) ? N_VOX : idx;          // zero row for invalid
        const unsigned short* p = feat_bf + (s << 5) + c0;
        asm volatile("global_load_dwordx4 %0, %1, off"
                     : "=v"(a[j]) : "v"(p));
    }
}

template <int K0, int KN>
__device__ __forceinline__ void mfma_chunk(const unsigned short* __restrict__ Wt,
                                           int colr, int c0,
                                           const bf16x8_t* a, f32x4_t* acc) {
    #pragma unroll
    for (int j = 0; j < KN; ++j) {
        const unsigned short* wk = Wt + (K0 + j) * (C_OUT * C_IN);
        #pragma unroll
        for (int t = 0; t < 4; ++t) {
            bf16x8_t b = *(const bf16x8_t*)(wk + (t * 16 + colr) * C_IN + c0);
            acc[t] = __builtin_amdgcn_mfma_f32_16x16x32_bf16(a[j], b, acc[t], 0, 0, 0);
        }
    }
}

#define WAIT_VM0() do { \
    asm volatile("s_waitcnt vmcnt(0)" ::: "memory"); \
    __builtin_amdgcn_sched_barrier(0); \
} while (0)

template <bool BF>
__global__ __launch_bounds__(256, 2) void conv_kernel(
    const float* __restrict__ feat_f32,
    const unsigned short* __restrict__ feat_bf,
    const int* __restrict__ nidx,
    const unsigned short* __restrict__ Wt,
    float* __restrict__ out, float* __restrict__ partials)
{
    __shared__ float lsum[4][C_OUT];
    __shared__ float lsq[4][C_OUT];

    const int wid  = threadIdx.x >> 6;
    const int lane = threadIdx.x & 63;
    const int colr = lane & 15;   // A row (voxel) / C col (channel)
    const int kch  = lane >> 4;   // k-chunk 0..3
    const int c0   = kch * 8;     // input-channel start of fragment
    const int base = blockIdx.x * 64 + wid * 16;
    const int vox  = base + colr;
    const bool valid = (vox < N_VOX);
    const int force = valid ? 0 : -1;            // idx|force = -1 for pad rows
    const int* nrow = nidx + (valid ? vox : 0) * KOFF;

    f32x4_t acc[4];
    #pragma unroll
    for (int t = 0; t < 4; ++t) acc[t] = (f32x4_t)0.0f;

    if constexpr (BF) {
        int idxs[KOFF];
        #pragma unroll
        for (int k = 0; k < KOFF; ++k) idxs[k] = nrow[k] | force;

        bf16x8_t aA[9], aB[9], aC[9];
        gather_chunk<0, 9>(feat_bf, idxs, c0, aA);
        WAIT_VM0();                                   // aA ready
        gather_chunk<9, 9>(feat_bf, idxs, c0, aB);    // in flight during A MFMAs
        mfma_chunk<0, 9>(Wt, colr, c0, aA, acc);
        WAIT_VM0();                                   // aB ready
        gather_chunk<18, 9>(feat_bf, idxs, c0, aC);   // in flight during B MFMAs
        mfma_chunk<9, 9>(Wt, colr, c0, aB, acc);
        WAIT_VM0();                                   // aC ready
        mfma_chunk<18, 9>(Wt, colr, c0, aC, acc);
    } else {
        // fallback (ws too small): shallow-pipeline f32 path
        int idx = valid ? nrow[0] : -1;
        for (int k = 0; k < KOFF; ++k) {
            int idx_next = (k < KOFF - 1 && valid) ? nrow[k + 1] : -1;
            if (__any(idx >= 0)) {
                bf16x8_t a = (bf16x8_t)(short)0;
                if (idx >= 0) {
                    const f32x4_t* fp = (const f32x4_t*)(feat_f32 + (idx << 5) + c0);
                    f32x4_t f0 = fp[0], f1 = fp[1];
                    a[0] = f2bf(f0[0]); a[1] = f2bf(f0[1]);
                    a[2] = f2bf(f0[2]); a[3] = f2bf(f0[3]);
                    a[4] = f2bf(f1[0]); a[5] = f2bf(f1[1]);
                    a[6] = f2bf(f1[2]); a[7] = f2bf(f1[3]);
                }
                const unsigned short* wk = Wt + k * (C_OUT * C_IN);
                #pragma unroll
                for (int t = 0; t < 4; ++t) {
                    bf16x8_t b = *(const bf16x8_t*)(wk + (t * 16 + colr) * C_IN + c0);
                    acc[t] = __builtin_amdgcn_mfma_f32_16x16x32_bf16(a, b, acc[t], 0, 0, 0);
                }
            }
            idx = idx_next;
        }
    }

    // epilogue: C/D layout col = lane&15, row = (lane>>4)*4 + i
    float psum[4], psq[4];
    #pragma unroll
    for (int t = 0; t < 4; ++t) { psum[t] = 0.f; psq[t] = 0.f; }

    #pragma unroll
    for (int t = 0; t < 4; ++t) {
        #pragma unroll
        for (int i = 0; i < 4; ++i) {
            int v = base + kch * 4 + i;
            float x = acc[t][i];
            if (v < N_VOX) out[v * C_OUT + t * 16 + colr] = x;
            psum[t] += x;           // pad rows are exactly 0
            psq[t]  += x * x;
        }
    }

    #pragma unroll
    for (int t = 0; t < 4; ++t) {
        psum[t] += __shfl_xor(psum[t], 16);
        psum[t] += __shfl_xor(psum[t], 32);
        psq[t]  += __shfl_xor(psq[t], 16);
        psq[t]  += __shfl_xor(psq[t], 32);
    }
    if (lane < 16) {
        #pragma unroll
        for (int t = 0; t < 4; ++t) {
            lsum[wid][t * 16 + lane] = psum[t];
            lsq[wid][t * 16 + lane]  = psq[t];
        }
    }
    __syncthreads();
    // channel-major partials: rows 0..63 = sum[c], rows 64..127 = sumsq[c]
    if (threadIdx.x < 128) {
        int c = threadIdx.x & 63;
        float s;
        if (threadIdx.x < 64)
            s = lsum[0][c] + lsum[1][c] + lsum[2][c] + lsum[3][c];
        else
            s = lsq[0][c] + lsq[1][c] + lsq[2][c] + lsq[3][c];
        partials[threadIdx.x * NB_CONV + blockIdx.x] = s;
    }
}

// one block per output channel: coalesced reduction over NB_CONV partials
__global__ __launch_bounds__(256) void stats_kernel(
    const float* __restrict__ partials,
    const float* __restrict__ gamma, const float* __restrict__ beta,
    float* __restrict__ ss)
{
    __shared__ float bs[4], bq[4];
    const int c = blockIdx.x;
    const float* ps = partials + c * NB_CONV;
    const float* pq = partials + (64 + c) * NB_CONV;
    float s = 0.f, q = 0.f;
    for (int i = threadIdx.x; i < NB_CONV; i += 256) {
        s += ps[i];
        q += pq[i];
    }
    #pragma unroll
    for (int o = 1; o < 64; o <<= 1) {
        s += __shfl_xor(s, o);
        q += __shfl_xor(q, o);
    }
    int wid = threadIdx.x >> 6, lane = threadIdx.x & 63;
    if (lane == 0) { bs[wid] = s; bq[wid] = q; }
    __syncthreads();
    if (threadIdx.x == 0) {
        float S = bs[0] + bs[1] + bs[2] + bs[3];
        float Q = bq[0] + bq[1] + bq[2] + bq[3];
        float mean = S * (1.0f / N_VOX);
        float var  = Q * (1.0f / N_VOX) - mean * mean;
        float inv  = rsqrtf(var + 1e-5f);
        float sc   = gamma[c] * inv;
        ss[c]      = sc;
        ss[64 + c] = beta[c] - mean * sc;
    }
}

__global__ void bn_relu_kernel(float* __restrict__ out,
                               const float* __restrict__ ss) {
    int i = blockIdx.x * 256 + threadIdx.x;  // exactly N*64/4 threads
    f32x4_t v = ((f32x4_t*)out)[i];
    int d0 = (i * 4) & 63;
    f32x4_t sc = *(const f32x4_t*)(ss + d0);
    f32x4_t sh = *(const f32x4_t*)(ss + 64 + d0);
    #pragma unroll
    for (int j = 0; j < 4; ++j) v[j] = fmaxf(v[j] * sc[j] + sh[j], 0.f);
    ((f32x4_t*)out)[i] = v;
}

extern "C" void kernel_launch(void* const* d_in, const int* in_sizes, int n_in,
                              void* d_out, int out_size, void* d_ws, size_t ws_size,
                              hipStream_t stream) {
    const float* feat  = (const float*)d_in[0];
    const int*   nidx  = (const int*)d_in[1];
    const float* W     = (const float*)d_in[2];
    const float* gamma = (const float*)d_in[3];
    const float* beta  = (const float*)d_in[4];
    float* out = (float*)d_out;

    char* ws = (char*)d_ws;
    const size_t wt_bytes = KOFF * C_OUT * C_IN * 2;          // 110592
    const size_t fb_bytes = (size_t)(N_VOX + 1) * C_IN * 2;   // 6400064
    const size_t pt_bytes = 128 * NB_CONV * 4;                // 800256

    unsigned short* Wt = (unsigned short*)ws;
    const bool bf_ok = ws_size >= wt_bytes + fb_bytes + pt_bytes + 512;

    unsigned short* feat_bf;
    float* partials;
    if (bf_ok) {
        feat_bf  = (unsigned short*)(ws + wt_bytes);
        partials = (float*)(ws + wt_bytes + fb_bytes);
    } else {
        feat_bf  = nullptr;
        partials = (float*)(ws + wt_bytes);
    }
    float* ss = partials + 128 * NB_CONV;

    if (bf_ok) {
        int feat_blocks = (((N_VOX + 1) * C_IN) / 8 + 255) / 256;  // 1563
        prep_kernel<<<WT_BLOCKS + feat_blocks, 256, 0, stream>>>(W, Wt, feat, feat_bf);
        conv_kernel<true><<<NB_CONV, 256, 0, stream>>>(feat, feat_bf, nidx, Wt, out, partials);
    } else {
        int wt_elems = KOFF * C_OUT * C_IN;
        prep_kernel<<<WT_BLOCKS, 256, 0, stream>>>(W, Wt, feat, (unsigned short*)ws);
        conv_kernel<false><<<NB_CONV, 256, 0, stream>>>(feat, feat_bf, nidx, Wt, out, partials);
    }
    stats_kernel<<<C_OUT, 256, 0, stream>>>(partials, gamma, beta, ss);
    bn_relu_kernel<<<(N_VOX * C_OUT / 4 + 255) / 256, 256, 0, stream>>>(out, ss);
}

// Round 6
// 62.555 us; speedup vs baseline: 1.3869x; 1.2933x over previous
//
#include <hip/hip_runtime.h>
#include <hip/hip_bf16.h>

#define N_VOX 100000
#define C_IN  32
#define C_OUT 64
#define KOFF  27
#define VPB   128              // voxels per block: 8 waves x 16
#define NB_CONV 782            // ceil(100000/128)
#define WT_BLOCKS 216          // 27*64*32 / 256
#define WT_HALFS (KOFF * C_OUT * C_IN)   // 55296
#define WT_BYTES (WT_HALFS * 2)          // 110592

typedef __attribute__((ext_vector_type(8))) short bf16x8_t;
typedef __attribute__((ext_vector_type(4))) float f32x4_t;

__device__ __forceinline__ short f2bf(float f) {
    __hip_bfloat16 h = __float2bfloat16(f);
    return __builtin_bit_cast(short, h);
}

// combined prep: blocks [0,216) transpose W -> Wt[k][d][c] bf16;
// blocks [216,...) convert features f32 -> bf16 (+ zero row at N_VOX)
__global__ void prep_kernel(const float* __restrict__ W,
                            unsigned short* __restrict__ Wt,
                            const float* __restrict__ feat,
                            unsigned short* __restrict__ fb) {
    int bid = blockIdx.x;
    if (bid < WT_BLOCKS) {
        int i = bid * 256 + threadIdx.x;   // exactly 55296 threads
        int c = i & 31;
        int d = (i >> 5) & 63;
        int k = i >> 11;
        Wt[i] = (unsigned short)f2bf(W[k * (C_IN * C_OUT) + c * C_OUT + d]);
    } else {
        int t = (bid - WT_BLOCKS) * 256 + threadIdx.x;  // one thread per 8 elems
        const int total8 = ((N_VOX + 1) * C_IN) / 8;    // 400004
        if (t >= total8) return;
        int e = t * 8;
        bf16x8_t o;
        if (e < N_VOX * C_IN) {
            const f32x4_t* fp = (const f32x4_t*)(feat + e);
            f32x4_t f0 = fp[0], f1 = fp[1];
            o[0] = f2bf(f0[0]); o[1] = f2bf(f0[1]); o[2] = f2bf(f0[2]); o[3] = f2bf(f0[3]);
            o[4] = f2bf(f1[0]); o[5] = f2bf(f1[1]); o[6] = f2bf(f1[2]); o[7] = f2bf(f1[3]);
        } else {
            o = (bf16x8_t)(short)0;
        }
        *(bf16x8_t*)(fb + e) = o;
    }
}

// one 9-k MFMA chunk; B comes from swizzled LDS (lgkmcnt only, no VMEM).
// K0 must be a literal so a[] indexing stays compile-time (no scratch).
#define DO_CHUNK(K0)                                                          \
    do {                                                                      \
        _Pragma("unroll")                                                     \
        for (int j_ = 0; j_ < 9; ++j_) {                                      \
            const int k_ = (K0) + j_;                                         \
            _Pragma("unroll")                                                 \
            for (int t_ = 0; t_ < 4; ++t_) {                                  \
                int r_ = t_ * 16 + colr;                                      \
                int o_ = (k_ << 12) + (r_ << 6) + (kch << 4);                 \
                o_ ^= (r_ & 7) << 4;                                          \
                bf16x8_t b_ = *(const bf16x8_t*)((const char*)wt_lds + o_);   \
                acc[t_] = __builtin_amdgcn_mfma_f32_16x16x32_bf16(            \
                    a[k_], b_, acc[t_], 0, 0, 0);                             \
            }                                                                 \
        }                                                                     \
    } while (0)

template <bool BF>
__global__ __launch_bounds__(512, 2) void conv_kernel(
    const float* __restrict__ feat_f32,
    const unsigned short* __restrict__ feat_bf,
    const int* __restrict__ nidx,
    const unsigned short* __restrict__ Wt,
    float* __restrict__ out, float* __restrict__ partials)
{
    __shared__ unsigned short wt_lds[WT_HALFS];   // 110592 B, XOR-swizzled
    __shared__ float lsum[8][C_OUT];
    __shared__ float lsq[8][C_OUT];

    const int tid  = threadIdx.x;
    const int wid  = tid >> 6;
    const int lane = tid & 63;
    const int colr = lane & 15;   // A row (voxel) / C col (channel)
    const int kch  = lane >> 4;   // k-chunk 0..3
    const int base = blockIdx.x * VPB + wid * 16;
    const int vox  = base + colr;
    const bool valid = (vox < N_VOX);
    const int force = valid ? 0 : -1;            // idx|force = -1 for pad rows
    const int* nrow = nidx + (valid ? vox : 0) * KOFF;

    // ---- stage Wt into LDS, swizzle byte o -> o ^ (((o>>6)&7)<<4) ----
    for (int j = tid; j < WT_HALFS / 8; j += 512) {
        int o = j * 16;
        bf16x8_t v = *(const bf16x8_t*)((const char*)Wt + o);
        int so = o ^ (((o >> 6) & 7) << 4);
        *(bf16x8_t*)((char*)wt_lds + so) = v;
    }
    __syncthreads();

    f32x4_t acc[4];
    #pragma unroll
    for (int t = 0; t < 4; ++t) acc[t] = (f32x4_t)0.0f;

    if constexpr (BF) {
        // phase 1: all indices + all 32-bit byte offsets (compiler VMEM drains here)
        int idxs[KOFF];
        #pragma unroll
        for (int k = 0; k < KOFF; ++k) idxs[k] = nrow[k] | force;
        unsigned off[KOFF];
        #pragma unroll
        for (int k = 0; k < KOFF; ++k) {
            int s = (idxs[k] < 0) ? N_VOX : idxs[k];   // zero row if invalid
            off[k] = ((unsigned)s << 6) + (unsigned)(kch << 4);
        }
        __builtin_amdgcn_sched_barrier(0);

        // phase 2: one burst of 27 asm gathers -> vmcnt holds exactly these
        bf16x8_t a[KOFF];
        #pragma unroll
        for (int k = 0; k < KOFF; ++k)
            asm volatile("global_load_dwordx4 %0, %1, %2"
                         : "=v"(a[k]) : "v"(off[k]), "s"(feat_bf));
        __builtin_amdgcn_sched_barrier(0);

        // phase 3: counted-wait MFMA chunks (B from LDS only)
        asm volatile("s_waitcnt vmcnt(18)" ::: "memory");   // a[0..8] ready
        __builtin_amdgcn_sched_barrier(0);
        DO_CHUNK(0);
        asm volatile("s_waitcnt vmcnt(9)" ::: "memory");    // a[9..17] ready
        __builtin_amdgcn_sched_barrier(0);
        DO_CHUNK(9);
        asm volatile("s_waitcnt vmcnt(0)" ::: "memory");    // a[18..26] ready
        __builtin_amdgcn_sched_barrier(0);
        DO_CHUNK(18);
    } else {
        // fallback (ws too small): shallow f32 path, B from LDS
        int idx = valid ? nrow[0] : -1;
        for (int k = 0; k < KOFF; ++k) {
            int idx_next = (k < KOFF - 1 && valid) ? nrow[k + 1] : -1;
            if (__any(idx >= 0)) {
                bf16x8_t av = (bf16x8_t)(short)0;
                if (idx >= 0) {
                    const f32x4_t* fp = (const f32x4_t*)(feat_f32 + (idx << 5) + kch * 8);
                    f32x4_t f0 = fp[0], f1 = fp[1];
                    av[0] = f2bf(f0[0]); av[1] = f2bf(f0[1]);
                    av[2] = f2bf(f0[2]); av[3] = f2bf(f0[3]);
                    av[4] = f2bf(f1[0]); av[5] = f2bf(f1[1]);
                    av[6] = f2bf(f1[2]); av[7] = f2bf(f1[3]);
                }
                #pragma unroll
                for (int t = 0; t < 4; ++t) {
                    int r = t * 16 + colr;
                    int o = (k << 12) + (r << 6) + (kch << 4);
                    o ^= (r & 7) << 4;
                    bf16x8_t b = *(const bf16x8_t*)((const char*)wt_lds + o);
                    acc[t] = __builtin_amdgcn_mfma_f32_16x16x32_bf16(av, b, acc[t], 0, 0, 0);
                }
            }
            idx = idx_next;
        }
    }

    // epilogue: C/D layout col = lane&15, row = (lane>>4)*4 + i
    float psum[4], psq[4];
    #pragma unroll
    for (int t = 0; t < 4; ++t) { psum[t] = 0.f; psq[t] = 0.f; }

    #pragma unroll
    for (int t = 0; t < 4; ++t) {
        #pragma unroll
        for (int i = 0; i < 4; ++i) {
            int v = base + kch * 4 + i;
            float x = acc[t][i];
            if (v < N_VOX) out[v * C_OUT + t * 16 + colr] = x;
            psum[t] += x;           // pad rows are exactly 0
            psq[t]  += x * x;
        }
    }

    #pragma unroll
    for (int t = 0; t < 4; ++t) {
        psum[t] += __shfl_xor(psum[t], 16);
        psum[t] += __shfl_xor(psum[t], 32);
        psq[t]  += __shfl_xor(psq[t], 16);
        psq[t]  += __shfl_xor(psq[t], 32);
    }
    if (lane < 16) {
        #pragma unroll
        for (int t = 0; t < 4; ++t) {
            lsum[wid][t * 16 + lane] = psum[t];
            lsq[wid][t * 16 + lane]  = psq[t];
        }
    }
    __syncthreads();
    // channel-major partials: rows 0..63 = sum[c], rows 64..127 = sumsq[c]
    if (tid < 128) {
        int c = tid & 63;
        float s = 0.f;
        if (tid < 64) {
            #pragma unroll
            for (int w = 0; w < 8; ++w) s += lsum[w][c];
        } else {
            #pragma unroll
            for (int w = 0; w < 8; ++w) s += lsq[w][c];
        }
        partials[tid * NB_CONV + blockIdx.x] = s;
    }
}

// one block per output channel: coalesced reduction over NB_CONV partials
__global__ __launch_bounds__(256) void stats_kernel(
    const float* __restrict__ partials,
    const float* __restrict__ gamma, const float* __restrict__ beta,
    float* __restrict__ ss)
{
    __shared__ float bs[4], bq[4];
    const int c = blockIdx.x;
    const float* ps = partials + c * NB_CONV;
    const float* pq = partials + (64 + c) * NB_CONV;
    float s = 0.f, q = 0.f;
    for (int i = threadIdx.x; i < NB_CONV; i += 256) {
        s += ps[i];
        q += pq[i];
    }
    #pragma unroll
    for (int o = 1; o < 64; o <<= 1) {
        s += __shfl_xor(s, o);
        q += __shfl_xor(q, o);
    }
    int wid = threadIdx.x >> 6, lane = threadIdx.x & 63;
    if (lane == 0) { bs[wid] = s; bq[wid] = q; }
    __syncthreads();
    if (threadIdx.x == 0) {
        float S = bs[0] + bs[1] + bs[2] + bs[3];
        float Q = bq[0] + bq[1] + bq[2] + bq[3];
        float mean = S * (1.0f / N_VOX);
        float var  = Q * (1.0f / N_VOX) - mean * mean;
        float inv  = rsqrtf(var + 1e-5f);
        float sc   = gamma[c] * inv;
        ss[c]      = sc;
        ss[64 + c] = beta[c] - mean * sc;
    }
}

__global__ void bn_relu_kernel(float* __restrict__ out,
                               const float* __restrict__ ss) {
    int i = blockIdx.x * 256 + threadIdx.x;  // exactly N*64/4 threads
    f32x4_t v = ((f32x4_t*)out)[i];
    int d0 = (i * 4) & 63;
    f32x4_t sc = *(const f32x4_t*)(ss + d0);
    f32x4_t sh = *(const f32x4_t*)(ss + 64 + d0);
    #pragma unroll
    for (int j = 0; j < 4; ++j) v[j] = fmaxf(v[j] * sc[j] + sh[j], 0.f);
    ((f32x4_t*)out)[i] = v;
}

extern "C" void kernel_launch(void* const* d_in, const int* in_sizes, int n_in,
                              void* d_out, int out_size, void* d_ws, size_t ws_size,
                              hipStream_t stream) {
    const float* feat  = (const float*)d_in[0];
    const int*   nidx  = (const int*)d_in[1];
    const float* W     = (const float*)d_in[2];
    const float* gamma = (const float*)d_in[3];
    const float* beta  = (const float*)d_in[4];
    float* out = (float*)d_out;

    char* ws = (char*)d_ws;
    const size_t wt_bytes = WT_BYTES;                         // 110592
    const size_t fb_bytes = (size_t)(N_VOX + 1) * C_IN * 2;   // 6400064
    const size_t pt_bytes = 128 * NB_CONV * 4;                // 400384

    unsigned short* Wt = (unsigned short*)ws;
    const bool bf_ok = ws_size >= wt_bytes + fb_bytes + pt_bytes + 512;

    unsigned short* feat_bf;
    float* partials;
    if (bf_ok) {
        feat_bf  = (unsigned short*)(ws + wt_bytes);
        partials = (float*)(ws + wt_bytes + fb_bytes);
    } else {
        feat_bf  = nullptr;
        partials = (float*)(ws + wt_bytes);
    }
    float* ss = partials + 128 * NB_CONV;

    if (bf_ok) {
        int feat_blocks = (((N_VOX + 1) * C_IN) / 8 + 255) / 256;  // 1563
        prep_kernel<<<WT_BLOCKS + feat_blocks, 256, 0, stream>>>(W, Wt, feat, feat_bf);
        conv_kernel<true><<<NB_CONV, 512, 0, stream>>>(feat, feat_bf, nidx, Wt, out, partials);
    } else {
        prep_kernel<<<WT_BLOCKS, 256, 0, stream>>>(W, Wt, feat, (unsigned short*)ws);
        conv_kernel<false><<<NB_CONV, 512, 0, stream>>>(feat, feat_bf, nidx, Wt, out, partials);
    }
    stats_kernel<<<C_OUT, 256, 0, stream>>>(partials, gamma, beta, ss);
    bn_relu_kernel<<<(N_VOX * C_OUT / 4 + 255) / 256, 256, 0, stream>>>(out, ss);
}

// Round 8
// 47.741 us; speedup vs baseline: 1.8173x; 1.3103x over previous
//
#include <hip/hip_runtime.h>
#include <hip/hip_bf16.h>

#define N_VOX 100000
#define C_IN  32
#define C_OUT 64
#define KOFF  27
#define CONV_T 1024
#define VPB    256             // 16 waves x 16 voxels per block
#define NB_CONV 391            // ceil(100000/256)
#define WT_BLOCKS 216          // 27*64*32 / 256
#define WT_HALFS (KOFF * C_OUT * C_IN)   // 55296 bf16 elements
#define WT_BYTES (WT_HALFS * 2)          // 110592 B

typedef __attribute__((ext_vector_type(8))) short bf16x8_t;
typedef __attribute__((ext_vector_type(4))) float f32x4_t;

__device__ __forceinline__ short f2bf(float f) {
    __hip_bfloat16 h = __float2bfloat16(f);
    return __builtin_bit_cast(short, h);
}
__device__ __forceinline__ float bf2f(unsigned short u) {
    return __builtin_bit_cast(float, (unsigned)u << 16);
}

// prep: blocks [0,216): Wt PRE-SWIZZLED: element (k,d,c) -> linear index
// (k<<11|d<<5|c) ^ ((d&7)<<3)  == byte offset XOR ((d&7)<<4); a LINEAR
// global->LDS copy then preserves the bank swizzle (round-6-verified XOR).
// blocks [216,...): features f32 -> bf16 (+ zero row at N_VOX)
__global__ void prep_kernel(const float* __restrict__ W,
                            unsigned short* __restrict__ Wt,
                            const float* __restrict__ feat,
                            unsigned short* __restrict__ fb) {
    int bid = blockIdx.x;
    if (bid < WT_BLOCKS) {
        int i = bid * 256 + threadIdx.x;   // exactly 55296
        int c = i & 31;
        int d = (i >> 5) & 63;
        int k = i >> 11;
        int dst = i ^ ((d & 7) << 3);
        Wt[dst] = (unsigned short)f2bf(W[k * (C_IN * C_OUT) + c * C_OUT + d]);
    } else {
        int t = (bid - WT_BLOCKS) * 256 + threadIdx.x;
        const int total8 = ((N_VOX + 1) * C_IN) / 8;    // 400004
        if (t >= total8) return;
        int e = t * 8;
        bf16x8_t o;
        if (e < N_VOX * C_IN) {
            const f32x4_t* fp = (const f32x4_t*)(feat + e);
            f32x4_t f0 = fp[0], f1 = fp[1];
            o[0] = f2bf(f0[0]); o[1] = f2bf(f0[1]); o[2] = f2bf(f0[2]); o[3] = f2bf(f0[3]);
            o[4] = f2bf(f1[0]); o[5] = f2bf(f1[1]); o[6] = f2bf(f1[2]); o[7] = f2bf(f1[3]);
        } else {
            o = (bf16x8_t)(short)0;
        }
        *(bf16x8_t*)(fb + e) = o;
    }
}

#define GLOAD(dst, voff)                                                      \
    asm volatile("global_load_dwordx4 %0, %1, %2"                             \
                 : "=v"(dst) : "v"(voff), "s"(feat_bf))

#define VMW(n) do {                                                           \
    asm volatile("s_waitcnt vmcnt(" #n ")" ::: "memory");                     \
    __builtin_amdgcn_sched_barrier(0);                                        \
} while (0)

// one 9-k MFMA chunk; B from swizzled LDS (lgkmcnt only, no VMEM).
#define DO_CHUNK(K0, A0)                                                      \
    do {                                                                      \
        _Pragma("unroll")                                                     \
        for (int j_ = 0; j_ < 9; ++j_) {                                      \
            _Pragma("unroll")                                                 \
            for (int t_ = 0; t_ < 4; ++t_) {                                  \
                const int r_ = t_ * 16 + colr;                                \
                int o_ = (((K0) + j_) << 12) + (r_ << 6) + (kch << 4);        \
                o_ ^= (r_ & 7) << 4;                                          \
                bf16x8_t b_ = *(const bf16x8_t*)((const char*)wt_lds + o_);   \
                acc[t_] = __builtin_amdgcn_mfma_f32_16x16x32_bf16(            \
                    a[(A0) + j_], b_, acc[t_], 0, 0, 0);                      \
            }                                                                 \
        }                                                                     \
    } while (0)

template <bool OUTBF>
__global__ __launch_bounds__(CONV_T, 4) void conv_kernel(
    const unsigned short* __restrict__ feat_bf,
    const int* __restrict__ nidx,
    const unsigned short* __restrict__ WtG,
    float* __restrict__ outf, unsigned short* __restrict__ outb,
    float* __restrict__ partials)
{
    __shared__ unsigned short wt_lds[WT_HALFS];   // 110592 B, swizzle pre-baked
    __shared__ float lsum[16][C_OUT];
    __shared__ float lsq[16][C_OUT];

    const int tid  = threadIdx.x;
    const int wid  = tid >> 6;
    const int lane = tid & 63;
    const int colr = lane & 15;
    const int kch  = lane >> 4;
    const int base = blockIdx.x * VPB + wid * 16;
    const int vox  = base + colr;
    const bool valid = (vox < N_VOX);
    const int force = valid ? 0 : -1;
    const int* nrow = nidx + (valid ? vox : 0) * KOFF;

    // phase 0: all 27 gather byte-offsets (nidx loads + waits live here)
    unsigned off[KOFF];
    #pragma unroll
    for (int k = 0; k < KOFF; ++k) {
        int idx = nrow[k] | force;
        int s = (idx < 0) ? N_VOX : idx;          // zero row for invalid
        off[k] = ((unsigned)s << 6) + (unsigned)(kch << 4);
    }
    __builtin_amdgcn_sched_barrier(0);

    // phase 1: stage weights via plain linear copy (round-6-proven); the
    // __syncthreads() fully drains vmcnt/lgkmcnt -> clean slate for counting
    for (int j = tid; j < WT_HALFS / 8; j += CONV_T)
        ((bf16x8_t*)wt_lds)[j] = ((const bf16x8_t*)WtG)[j];
    __syncthreads();

    f32x4_t acc[4];
    #pragma unroll
    for (int t = 0; t < 4; ++t) acc[t] = (f32x4_t)0.0f;

    // phase 2: 2-deep burst pipeline, 18 fragments live (72 VGPR)
    bf16x8_t a[18];
    #pragma unroll
    for (int k = 0; k < 18; ++k) GLOAD(a[k], off[k]);
    __builtin_amdgcn_sched_barrier(0);

    VMW(9);                               // a[0..8] ready (9 still in flight)
    DO_CHUNK(0, 0);
    #pragma unroll
    for (int j = 0; j < 9; ++j) GLOAD(a[j], off[18 + j]);   // reuse regs
    __builtin_amdgcn_sched_barrier(0);
    VMW(9);                               // a[9..17] ready (a18..26 in flight)
    DO_CHUNK(9, 9);
    VMW(0);                               // a[18..26] ready
    DO_CHUNK(18, 0);

    // epilogue: C/D layout col = lane&15, row = (lane>>4)*4 + i
    float psum[4], psq[4];
    #pragma unroll
    for (int t = 0; t < 4; ++t) { psum[t] = 0.f; psq[t] = 0.f; }

    #pragma unroll
    for (int t = 0; t < 4; ++t) {
        #pragma unroll
        for (int i = 0; i < 4; ++i) {
            int v = base + kch * 4 + i;
            float x = acc[t][i];
            if (v < N_VOX) {
                if constexpr (OUTBF)
                    outb[v * C_OUT + t * 16 + colr] = (unsigned short)f2bf(x);
                else
                    outf[v * C_OUT + t * 16 + colr] = x;
            }
            psum[t] += x;
            psq[t]  += x * x;
        }
    }

    #pragma unroll
    for (int t = 0; t < 4; ++t) {
        psum[t] += __shfl_xor(psum[t], 16);
        psum[t] += __shfl_xor(psum[t], 32);
        psq[t]  += __shfl_xor(psq[t], 16);
        psq[t]  += __shfl_xor(psq[t], 32);
    }
    if (lane < 16) {
        #pragma unroll
        for (int t = 0; t < 4; ++t) {
            lsum[wid][t * 16 + lane] = psum[t];
            lsq[wid][t * 16 + lane]  = psq[t];
        }
    }
    __syncthreads();
    if (tid < 128) {
        int c = tid & 63;
        float s = 0.f;
        if (tid < 64) {
            #pragma unroll
            for (int w = 0; w < 16; ++w) s += lsum[w][c];
        } else {
            #pragma unroll
            for (int w = 0; w < 16; ++w) s += lsq[w][c];
        }
        partials[tid * NB_CONV + blockIdx.x] = s;
    }
}

// fallback (tiny ws): f32 gather, shallow loop, B from pre-swizzled LDS
__global__ __launch_bounds__(CONV_T) void conv_fb_kernel(
    const float* __restrict__ feat,
    const int* __restrict__ nidx,
    const unsigned short* __restrict__ WtG,
    float* __restrict__ outf, float* __restrict__ partials)
{
    __shared__ unsigned short wt_lds[WT_HALFS];
    __shared__ float lsum[16][C_OUT];
    __shared__ float lsq[16][C_OUT];

    const int tid  = threadIdx.x;
    const int wid  = tid >> 6;
    const int lane = tid & 63;
    const int colr = lane & 15;
    const int kch  = lane >> 4;
    const int base = blockIdx.x * VPB + wid * 16;
    const int vox  = base + colr;
    const bool valid = (vox < N_VOX);
    const int* nrow = nidx + (valid ? vox : 0) * KOFF;

    for (int j = tid; j < WT_HALFS / 8; j += CONV_T)
        ((bf16x8_t*)wt_lds)[j] = ((const bf16x8_t*)WtG)[j];
    __syncthreads();

    f32x4_t acc[4];
    #pragma unroll
    for (int t = 0; t < 4; ++t) acc[t] = (f32x4_t)0.0f;

    for (int k = 0; k < KOFF; ++k) {
        int idx = valid ? nrow[k] : -1;
        bf16x8_t av = (bf16x8_t)(short)0;
        if (idx >= 0) {
            const f32x4_t* fp = (const f32x4_t*)(feat + (idx << 5) + kch * 8);
            f32x4_t f0 = fp[0], f1 = fp[1];
            av[0] = f2bf(f0[0]); av[1] = f2bf(f0[1]);
            av[2] = f2bf(f0[2]); av[3] = f2bf(f0[3]);
            av[4] = f2bf(f1[0]); av[5] = f2bf(f1[1]);
            av[6] = f2bf(f1[2]); av[7] = f2bf(f1[3]);
        }
        #pragma unroll
        for (int t = 0; t < 4; ++t) {
            int r = t * 16 + colr;
            int o = (k << 12) + (r << 6) + (kch << 4);
            o ^= (r & 7) << 4;
            bf16x8_t b = *(const bf16x8_t*)((const char*)wt_lds + o);
            acc[t] = __builtin_amdgcn_mfma_f32_16x16x32_bf16(av, b, acc[t], 0, 0, 0);
        }
    }

    float psum[4], psq[4];
    #pragma unroll
    for (int t = 0; t < 4; ++t) { psum[t] = 0.f; psq[t] = 0.f; }
    #pragma unroll
    for (int t = 0; t < 4; ++t) {
        #pragma unroll
        for (int i = 0; i < 4; ++i) {
            int v = base + kch * 4 + i;
            float x = acc[t][i];
            if (v < N_VOX) outf[v * C_OUT + t * 16 + colr] = x;
            psum[t] += x;
            psq[t]  += x * x;
        }
    }
    #pragma unroll
    for (int t = 0; t < 4; ++t) {
        psum[t] += __shfl_xor(psum[t], 16);
        psum[t] += __shfl_xor(psum[t], 32);
        psq[t]  += __shfl_xor(psq[t], 16);
        psq[t]  += __shfl_xor(psq[t], 32);
    }
    if (lane < 16) {
        #pragma unroll
        for (int t = 0; t < 4; ++t) {
            lsum[wid][t * 16 + lane] = psum[t];
            lsq[wid][t * 16 + lane]  = psq[t];
        }
    }
    __syncthreads();
    if (tid < 128) {
        int c = tid & 63;
        float s = 0.f;
        if (tid < 64) {
            #pragma unroll
            for (int w = 0; w < 16; ++w) s += lsum[w][c];
        } else {
            #pragma unroll
            for (int w = 0; w < 16; ++w) s += lsq[w][c];
        }
        partials[tid * NB_CONV + blockIdx.x] = s;
    }
}

__global__ __launch_bounds__(256) void stats_kernel(
    const float* __restrict__ partials,
    const float* __restrict__ gamma, const float* __restrict__ beta,
    float* __restrict__ ss)
{
    __shared__ float bs[4], bq[4];
    const int c = blockIdx.x;
    const float* ps = partials + c * NB_CONV;
    const float* pq = partials + (64 + c) * NB_CONV;
    float s = 0.f, q = 0.f;
    for (int i = threadIdx.x; i < NB_CONV; i += 256) {
        s += ps[i];
        q += pq[i];
    }
    #pragma unroll
    for (int o = 1; o < 64; o <<= 1) {
        s += __shfl_xor(s, o);
        q += __shfl_xor(q, o);
    }
    int wid = threadIdx.x >> 6, lane = threadIdx.x & 63;
    if (lane == 0) { bs[wid] = s; bq[wid] = q; }
    __syncthreads();
    if (threadIdx.x == 0) {
        float S = bs[0] + bs[1] + bs[2] + bs[3];
        float Q = bq[0] + bq[1] + bq[2] + bq[3];
        float mean = S * (1.0f / N_VOX);
        float var  = Q * (1.0f / N_VOX) - mean * mean;
        float inv  = rsqrtf(var + 1e-5f);
        float sc   = gamma[c] * inv;
        ss[c]      = sc;
        ss[64 + c] = beta[c] - mean * sc;
    }
}

// bf16 intermediate -> f32 output
__global__ void bn_relu_b_kernel(const unsigned short* __restrict__ cbf,
                                 const float* __restrict__ ss,
                                 float* __restrict__ out) {
    int i = blockIdx.x * 256 + threadIdx.x;   // exactly N*64/8 threads
    bf16x8_t v = ((const bf16x8_t*)cbf)[i];
    int d0 = (i * 8) & 63;
    f32x4_t sc0 = *(const f32x4_t*)(ss + d0);
    f32x4_t sc1 = *(const f32x4_t*)(ss + d0 + 4);
    f32x4_t sh0 = *(const f32x4_t*)(ss + 64 + d0);
    f32x4_t sh1 = *(const f32x4_t*)(ss + 64 + d0 + 4);
    f32x4_t o0, o1;
    #pragma unroll
    for (int j = 0; j < 4; ++j) {
        o0[j] = fmaxf(bf2f((unsigned short)v[j]) * sc0[j] + sh0[j], 0.f);
        o1[j] = fmaxf(bf2f((unsigned short)v[j + 4]) * sc1[j] + sh1[j], 0.f);
    }
    ((f32x4_t*)out)[2 * i]     = o0;
    ((f32x4_t*)out)[2 * i + 1] = o1;
}

// f32 in-place
__global__ void bn_relu_f_kernel(float* __restrict__ out,
                                 const float* __restrict__ ss) {
    int i = blockIdx.x * 256 + threadIdx.x;  // exactly N*64/4 threads
    f32x4_t v = ((f32x4_t*)out)[i];
    int d0 = (i * 4) & 63;
    f32x4_t sc = *(const f32x4_t*)(ss + d0);
    f32x4_t sh = *(const f32x4_t*)(ss + 64 + d0);
    #pragma unroll
    for (int j = 0; j < 4; ++j) v[j] = fmaxf(v[j] * sc[j] + sh[j], 0.f);
    ((f32x4_t*)out)[i] = v;
}

extern "C" void kernel_launch(void* const* d_in, const int* in_sizes, int n_in,
                              void* d_out, int out_size, void* d_ws, size_t ws_size,
                              hipStream_t stream) {
    const float* feat  = (const float*)d_in[0];
    const int*   nidx  = (const int*)d_in[1];
    const float* W     = (const float*)d_in[2];
    const float* gamma = (const float*)d_in[3];
    const float* beta  = (const float*)d_in[4];
    float* out = (float*)d_out;

    char* ws = (char*)d_ws;
    const size_t wt_bytes  = WT_BYTES;                         // 110592
    const size_t fb_bytes  = (size_t)(N_VOX + 1) * C_IN * 2;   // 6400064
    const size_t cb_bytes  = (size_t)N_VOX * C_OUT * 2;        // 12800000
    const size_t pt_bytes  = 128 * NB_CONV * 4;                // 200192

    const bool bf_ok  = ws_size >= wt_bytes + fb_bytes + pt_bytes + 512;
    const bool cb_ok  = ws_size >= wt_bytes + fb_bytes + cb_bytes + pt_bytes + 512;

    unsigned short* Wt = (unsigned short*)ws;
    unsigned short* feat_bf = (unsigned short*)(ws + wt_bytes);
    unsigned short* cbf = (unsigned short*)(ws + wt_bytes + fb_bytes);
    float* partials;
    if (cb_ok)       partials = (float*)(ws + wt_bytes + fb_bytes + cb_bytes);
    else if (bf_ok)  partials = (float*)(ws + wt_bytes + fb_bytes);
    else             partials = (float*)(ws + wt_bytes);
    float* ss = partials + 128 * NB_CONV;

    if (bf_ok) {
        int feat_blocks = (((N_VOX + 1) * C_IN) / 8 + 255) / 256;  // 1563
        prep_kernel<<<WT_BLOCKS + feat_blocks, 256, 0, stream>>>(W, Wt, feat, feat_bf);
        if (cb_ok)
            conv_kernel<true><<<NB_CONV, CONV_T, 0, stream>>>(
                feat_bf, nidx, Wt, out, cbf, partials);
        else
            conv_kernel<false><<<NB_CONV, CONV_T, 0, stream>>>(
                feat_bf, nidx, Wt, out, cbf, partials);
    } else {
        prep_kernel<<<WT_BLOCKS, 256, 0, stream>>>(W, Wt, feat, Wt);
        conv_fb_kernel<<<NB_CONV, CONV_T, 0, stream>>>(feat, nidx, Wt, out, partials);
    }
    stats_kernel<<<C_OUT, 256, 0, stream>>>(partials, gamma, beta, ss);
    if (cb_ok)
        bn_relu_b_kernel<<<N_VOX * C_OUT / 8 / 256, 256, 0, stream>>>(cbf, ss, out);
    else
        bn_relu_f_kernel<<<N_VOX * C_OUT / 4 / 256, 256, 0, stream>>>(out, ss);
}

// Round 9
// 42.478 us; speedup vs baseline: 2.0424x; 1.1239x over previous
//
#include <hip/hip_runtime.h>
#include <hip/hip_bf16.h>

#define N_VOX 100000
#define C_IN  32
#define C_OUT 64
#define KOFF  27
#define CONV_T 512
#define GRID_C 256
#define VPB    256             // 8 waves x 32 voxels (M=32 per wave)
#define NT     391             // ceil(100000/256) tiles
#define NB_FB  782             // fallback tiles (VPB=128, M=16)
#define WT_BLOCKS 216          // 27*64*32 / 256
#define WT_HALFS (KOFF * C_OUT * C_IN)   // 55296 bf16
#define WT_BYTES (WT_HALFS * 2)          // 110592 B

typedef __attribute__((ext_vector_type(8))) short bf16x8_t;
typedef __attribute__((ext_vector_type(4))) float f32x4_t;

__device__ __forceinline__ short f2bf(float f) {
    __hip_bfloat16 h = __float2bfloat16(f);
    return __builtin_bit_cast(short, h);
}
__device__ __forceinline__ float bf2f(unsigned short u) {
    return __builtin_bit_cast(float, (unsigned)u << 16);
}

// prep: blocks [0,216): Wt PRE-SWIZZLED: element (k,d,c) -> linear index
// (k<<11|d<<5|c) ^ ((d&7)<<3); linear copy to LDS preserves the bank swizzle.
// blocks [216,...): features f32 -> bf16 (+ zero row at N_VOX)
__global__ void prep_kernel(const float* __restrict__ W,
                            unsigned short* __restrict__ Wt,
                            const float* __restrict__ feat,
                            unsigned short* __restrict__ fb) {
    int bid = blockIdx.x;
    if (bid < WT_BLOCKS) {
        int i = bid * 256 + threadIdx.x;   // exactly 55296
        int c = i & 31;
        int d = (i >> 5) & 63;
        int k = i >> 11;
        int dst = i ^ ((d & 7) << 3);
        Wt[dst] = (unsigned short)f2bf(W[k * (C_IN * C_OUT) + c * C_OUT + d]);
    } else {
        int t = (bid - WT_BLOCKS) * 256 + threadIdx.x;
        const int total8 = ((N_VOX + 1) * C_IN) / 8;    // 400004
        if (t >= total8) return;
        int e = t * 8;
        bf16x8_t o;
        if (e < N_VOX * C_IN) {
            const f32x4_t* fp = (const f32x4_t*)(feat + e);
            f32x4_t f0 = fp[0], f1 = fp[1];
            o[0] = f2bf(f0[0]); o[1] = f2bf(f0[1]); o[2] = f2bf(f0[2]); o[3] = f2bf(f0[3]);
            o[4] = f2bf(f1[0]); o[5] = f2bf(f1[1]); o[6] = f2bf(f1[2]); o[7] = f2bf(f1[3]);
        } else {
            o = (bf16x8_t)(short)0;
        }
        *(bf16x8_t*)(fb + e) = o;
    }
}

#define GLOAD(dst, voff)                                                      \
    asm volatile("global_load_dwordx4 %0, %1, %2"                             \
                 : "=v"(dst) : "v"(voff), "s"(feat_bf))

#define VMW(n) do {                                                           \
    asm volatile("s_waitcnt vmcnt(" #n ")" ::: "memory");                     \
    __builtin_amdgcn_sched_barrier(0);                                        \
} while (0)

template <bool OUTBF>
__global__ __launch_bounds__(CONV_T, 2) void conv_kernel(
    const unsigned short* __restrict__ feat_bf,
    const int* __restrict__ nidx,
    const unsigned short* __restrict__ WtG,
    float* __restrict__ outf, unsigned short* __restrict__ outb,
    float* __restrict__ partials)
{
    __shared__ unsigned short wt_lds[WT_HALFS];   // 110592 B, swizzle pre-baked
    __shared__ float lsum[8][C_OUT];
    __shared__ float lsq[8][C_OUT];

    const int tid  = threadIdx.x;
    const int wid  = tid >> 6;
    const int lane = tid & 63;
    const int colr = lane & 15;
    const int kch  = lane >> 4;

    // stage weights ONCE per block (persistent over tiles)
    for (int j = tid; j < WT_HALFS / 8; j += CONV_T)
        ((bf16x8_t*)wt_lds)[j] = ((const bf16x8_t*)WtG)[j];
    __syncthreads();

    float psum[4] = {0.f, 0.f, 0.f, 0.f};
    float psq[4]  = {0.f, 0.f, 0.f, 0.f};

    const int b  = blockIdx.x;
    const int bs = ((b & 7) << 5) | (b >> 3);     // bijective XCD swizzle (256)
    const int rr0 = NT % GRID_C;                   // 135
    const int t0  = bs + (bs < rr0 ? bs : rr0);    // bs*1 + min(bs, r)
    const int cnt = 1 + (bs < rr0 ? 1 : 0);

    for (int ti = 0; ti < cnt; ++ti) {
        const int base = (t0 + ti) * VPB + wid * 32;

        // phase 0: 54 gather byte-offsets (all compiler VMEM drains here;
        // previous tile ended with VMW(0) so counting starts clean)
        unsigned off[54];
        #pragma unroll
        for (int m = 0; m < 2; ++m) {
            int vx = base + m * 16 + colr;
            bool val = vx < N_VOX;
            const int* nr = nidx + (val ? vx : 0) * KOFF;
            int force = val ? 0 : -1;
            #pragma unroll
            for (int k = 0; k < KOFF; ++k) {
                int id = nr[k] | force;
                int s = (id < 0) ? N_VOX : id;    // zero row for invalid
                off[k * 2 + m] = ((unsigned)s << 6) + (unsigned)(kch << 4);
            }
        }
        __builtin_amdgcn_sched_barrier(0);

        f32x4_t acc0[4], acc1[4];
        #pragma unroll
        for (int t = 0; t < 4; ++t) { acc0[t] = (f32x4_t)0.0f; acc1[t] = (f32x4_t)0.0f; }

        // 2-chunk-deep burst: 12 fragments live (48 VGPR)
        bf16x8_t a[12];
        #pragma unroll
        for (int u = 0; u < 12; ++u) GLOAD(a[u], off[u]);
        __builtin_amdgcn_sched_barrier(0);

        // 9 chunks of 3 k-offsets; each b-read feeds TWO MFMAs (M=32)
        #pragma unroll
        for (int c = 0; c < 9; ++c) {
            if (c < 8) { VMW(6); } else { VMW(0); }
            const int ab = (c & 1) * 6;
            #pragma unroll
            for (int j = 0; j < 3; ++j) {
                const int kk = c * 3 + j;
                #pragma unroll
                for (int t = 0; t < 4; ++t) {
                    const int rw = t * 16 + colr;
                    int o = (kk << 12) + (rw << 6) + (kch << 4);
                    o ^= (rw & 7) << 4;
                    bf16x8_t bb = *(const bf16x8_t*)((const char*)wt_lds + o);
                    acc0[t] = __builtin_amdgcn_mfma_f32_16x16x32_bf16(
                        a[ab + j * 2 + 0], bb, acc0[t], 0, 0, 0);
                    acc1[t] = __builtin_amdgcn_mfma_f32_16x16x32_bf16(
                        a[ab + j * 2 + 1], bb, acc1[t], 0, 0, 0);
                }
            }
            if (c + 2 < 9) {
                const int nb2 = ((c + 2) & 1) * 6;
                #pragma unroll
                for (int u = 0; u < 6; ++u) GLOAD(a[nb2 + u], off[(c + 2) * 6 + u]);
                __builtin_amdgcn_sched_barrier(0);
            }
        }

        // epilogue: C/D col = lane&15 (channel), row = kch*4+i (voxel)
        #pragma unroll
        for (int t = 0; t < 4; ++t) {
            #pragma unroll
            for (int i = 0; i < 4; ++i) {
                int v0 = base + kch * 4 + i;
                int v1 = v0 + 16;
                int ch = t * 16 + colr;
                float x0 = acc0[t][i], x1 = acc1[t][i];
                if (v0 < N_VOX) {
                    if constexpr (OUTBF) outb[v0 * C_OUT + ch] = (unsigned short)f2bf(x0);
                    else                 outf[v0 * C_OUT + ch] = x0;
                }
                if (v1 < N_VOX) {
                    if constexpr (OUTBF) outb[v1 * C_OUT + ch] = (unsigned short)f2bf(x1);
                    else                 outf[v1 * C_OUT + ch] = x1;
                }
                psum[t] += x0 + x1;              // pad rows are exactly 0
                psq[t]  += x0 * x0 + x1 * x1;
            }
        }
    }

    #pragma unroll
    for (int t = 0; t < 4; ++t) {
        psum[t] += __shfl_xor(psum[t], 16);
        psum[t] += __shfl_xor(psum[t], 32);
        psq[t]  += __shfl_xor(psq[t], 16);
        psq[t]  += __shfl_xor(psq[t], 32);
    }
    if (lane < 16) {
        #pragma unroll
        for (int t = 0; t < 4; ++t) {
            lsum[wid][t * 16 + lane] = psum[t];
            lsq[wid][t * 16 + lane]  = psq[t];
        }
    }
    __syncthreads();
    if (tid < 128) {
        int c = tid & 63;
        float s = 0.f;
        if (tid < 64) {
            #pragma unroll
            for (int w = 0; w < 8; ++w) s += lsum[w][c];
        } else {
            #pragma unroll
            for (int w = 0; w < 8; ++w) s += lsq[w][c];
        }
        partials[tid * GRID_C + b] = s;
    }
}

// fallback (tiny ws): f32 gather, shallow loop, M=16, non-persistent
__global__ __launch_bounds__(CONV_T) void conv_fb_kernel(
    const float* __restrict__ feat,
    const int* __restrict__ nidx,
    const unsigned short* __restrict__ WtG,
    float* __restrict__ outf, float* __restrict__ partials)
{
    __shared__ unsigned short wt_lds[WT_HALFS];
    __shared__ float lsum[8][C_OUT];
    __shared__ float lsq[8][C_OUT];

    const int tid  = threadIdx.x;
    const int wid  = tid >> 6;
    const int lane = tid & 63;
    const int colr = lane & 15;
    const int kch  = lane >> 4;
    const int base = blockIdx.x * 128 + wid * 16;
    const int vox  = base + colr;
    const bool valid = (vox < N_VOX);
    const int* nrow = nidx + (valid ? vox : 0) * KOFF;

    for (int j = tid; j < WT_HALFS / 8; j += CONV_T)
        ((bf16x8_t*)wt_lds)[j] = ((const bf16x8_t*)WtG)[j];
    __syncthreads();

    f32x4_t acc[4];
    #pragma unroll
    for (int t = 0; t < 4; ++t) acc[t] = (f32x4_t)0.0f;

    for (int k = 0; k < KOFF; ++k) {
        int idx = valid ? nrow[k] : -1;
        bf16x8_t av = (bf16x8_t)(short)0;
        if (idx >= 0) {
            const f32x4_t* fp = (const f32x4_t*)(feat + (idx << 5) + kch * 8);
            f32x4_t f0 = fp[0], f1 = fp[1];
            av[0] = f2bf(f0[0]); av[1] = f2bf(f0[1]);
            av[2] = f2bf(f0[2]); av[3] = f2bf(f0[3]);
            av[4] = f2bf(f1[0]); av[5] = f2bf(f1[1]);
            av[6] = f2bf(f1[2]); av[7] = f2bf(f1[3]);
        }
        #pragma unroll
        for (int t = 0; t < 4; ++t) {
            int rw = t * 16 + colr;
            int o = (k << 12) + (rw << 6) + (kch << 4);
            o ^= (rw & 7) << 4;
            bf16x8_t bb = *(const bf16x8_t*)((const char*)wt_lds + o);
            acc[t] = __builtin_amdgcn_mfma_f32_16x16x32_bf16(av, bb, acc[t], 0, 0, 0);
        }
    }

    float psum[4], psq[4];
    #pragma unroll
    for (int t = 0; t < 4; ++t) { psum[t] = 0.f; psq[t] = 0.f; }
    #pragma unroll
    for (int t = 0; t < 4; ++t) {
        #pragma unroll
        for (int i = 0; i < 4; ++i) {
            int v = base + kch * 4 + i;
            float x = acc[t][i];
            if (v < N_VOX) outf[v * C_OUT + t * 16 + colr] = x;
            psum[t] += x;
            psq[t]  += x * x;
        }
    }
    #pragma unroll
    for (int t = 0; t < 4; ++t) {
        psum[t] += __shfl_xor(psum[t], 16);
        psum[t] += __shfl_xor(psum[t], 32);
        psq[t]  += __shfl_xor(psq[t], 16);
        psq[t]  += __shfl_xor(psq[t], 32);
    }
    if (lane < 16) {
        #pragma unroll
        for (int t = 0; t < 4; ++t) {
            lsum[wid][t * 16 + lane] = psum[t];
            lsq[wid][t * 16 + lane]  = psq[t];
        }
    }
    __syncthreads();
    if (tid < 128) {
        int c = tid & 63;
        float s = 0.f;
        if (tid < 64) {
            #pragma unroll
            for (int w = 0; w < 8; ++w) s += lsum[w][c];
        } else {
            #pragma unroll
            for (int w = 0; w < 8; ++w) s += lsq[w][c];
        }
        partials[tid * NB_FB + blockIdx.x] = s;
    }
}

__global__ __launch_bounds__(256) void stats_kernel(
    const float* __restrict__ partials, int nb,
    const float* __restrict__ gamma, const float* __restrict__ beta,
    float* __restrict__ ss)
{
    __shared__ float bs[4], bq[4];
    const int c = blockIdx.x;
    const float* ps = partials + c * nb;
    const float* pq = partials + (64 + c) * nb;
    float s = 0.f, q = 0.f;
    for (int i = threadIdx.x; i < nb; i += 256) {
        s += ps[i];
        q += pq[i];
    }
    #pragma unroll
    for (int o = 1; o < 64; o <<= 1) {
        s += __shfl_xor(s, o);
        q += __shfl_xor(q, o);
    }
    int wid = threadIdx.x >> 6, lane = threadIdx.x & 63;
    if (lane == 0) { bs[wid] = s; bq[wid] = q; }
    __syncthreads();
    if (threadIdx.x == 0) {
        float S = bs[0] + bs[1] + bs[2] + bs[3];
        float Q = bq[0] + bq[1] + bq[2] + bq[3];
        float mean = S * (1.0f / N_VOX);
        float var  = Q * (1.0f / N_VOX) - mean * mean;
        float inv  = rsqrtf(var + 1e-5f);
        float sc   = gamma[c] * inv;
        ss[c]      = sc;
        ss[64 + c] = beta[c] - mean * sc;
    }
}

// bf16 intermediate -> f32 output
__global__ void bn_relu_b_kernel(const unsigned short* __restrict__ cbf,
                                 const float* __restrict__ ss,
                                 float* __restrict__ out) {
    int i = blockIdx.x * 256 + threadIdx.x;   // exactly N*64/8 threads
    bf16x8_t v = ((const bf16x8_t*)cbf)[i];
    int d0 = (i * 8) & 63;
    f32x4_t sc0 = *(const f32x4_t*)(ss + d0);
    f32x4_t sc1 = *(const f32x4_t*)(ss + d0 + 4);
    f32x4_t sh0 = *(const f32x4_t*)(ss + 64 + d0);
    f32x4_t sh1 = *(const f32x4_t*)(ss + 64 + d0 + 4);
    f32x4_t o0, o1;
    #pragma unroll
    for (int j = 0; j < 4; ++j) {
        o0[j] = fmaxf(bf2f((unsigned short)v[j]) * sc0[j] + sh0[j], 0.f);
        o1[j] = fmaxf(bf2f((unsigned short)v[j + 4]) * sc1[j] + sh1[j], 0.f);
    }
    ((f32x4_t*)out)[2 * i]     = o0;
    ((f32x4_t*)out)[2 * i + 1] = o1;
}

// f32 in-place
__global__ void bn_relu_f_kernel(float* __restrict__ out,
                                 const float* __restrict__ ss) {
    int i = blockIdx.x * 256 + threadIdx.x;  // exactly N*64/4 threads
    f32x4_t v = ((f32x4_t*)out)[i];
    int d0 = (i * 4) & 63;
    f32x4_t sc = *(const f32x4_t*)(ss + d0);
    f32x4_t sh = *(const f32x4_t*)(ss + 64 + d0);
    #pragma unroll
    for (int j = 0; j < 4; ++j) v[j] = fmaxf(v[j] * sc[j] + sh[j], 0.f);
    ((f32x4_t*)out)[i] = v;
}

extern "C" void kernel_launch(void* const* d_in, const int* in_sizes, int n_in,
                              void* d_out, int out_size, void* d_ws, size_t ws_size,
                              hipStream_t stream) {
    const float* feat  = (const float*)d_in[0];
    const int*   nidx  = (const int*)d_in[1];
    const float* W     = (const float*)d_in[2];
    const float* gamma = (const float*)d_in[3];
    const float* beta  = (const float*)d_in[4];
    float* out = (float*)d_out;

    char* ws = (char*)d_ws;
    const size_t wt_bytes  = WT_BYTES;                         // 110592
    const size_t fb_bytes  = (size_t)(N_VOX + 1) * C_IN * 2;   // 6400064
    const size_t cb_bytes  = (size_t)N_VOX * C_OUT * 2;        // 12800000
    const size_t pt_bytes  = (size_t)128 * NB_FB * 4;          // 400384 (covers both)

    const bool bf_ok  = ws_size >= wt_bytes + fb_bytes + pt_bytes + 512;
    const bool cb_ok  = ws_size >= wt_bytes + fb_bytes + cb_bytes + pt_bytes + 512;

    unsigned short* Wt = (unsigned short*)ws;
    unsigned short* feat_bf = (unsigned short*)(ws + wt_bytes);
    unsigned short* cbf = (unsigned short*)(ws + wt_bytes + fb_bytes);
    float* partials;
    if (cb_ok)       partials = (float*)(ws + wt_bytes + fb_bytes + cb_bytes);
    else if (bf_ok)  partials = (float*)(ws + wt_bytes + fb_bytes);
    else             partials = (float*)(ws + wt_bytes);
    float* ss = partials + 128 * NB_FB;

    if (bf_ok) {
        int feat_blocks = (((N_VOX + 1) * C_IN) / 8 + 255) / 256;  // 1563
        prep_kernel<<<WT_BLOCKS + feat_blocks, 256, 0, stream>>>(W, Wt, feat, feat_bf);
        if (cb_ok)
            conv_kernel<true><<<GRID_C, CONV_T, 0, stream>>>(
                feat_bf, nidx, Wt, out, cbf, partials);
        else
            conv_kernel<false><<<GRID_C, CONV_T, 0, stream>>>(
                feat_bf, nidx, Wt, out, cbf, partials);
        stats_kernel<<<C_OUT, 256, 0, stream>>>(partials, GRID_C, gamma, beta, ss);
    } else {
        prep_kernel<<<WT_BLOCKS, 256, 0, stream>>>(W, Wt, feat, Wt);
        conv_fb_kernel<<<NB_FB, CONV_T, 0, stream>>>(feat, nidx, Wt, out, partials);
        stats_kernel<<<C_OUT, 256, 0, stream>>>(partials, NB_FB, gamma, beta, ss);
    }
    if (cb_ok)
        bn_relu_b_kernel<<<N_VOX * C_OUT / 8 / 256, 256, 0, stream>>>(cbf, ss, out);
    else
        bn_relu_f_kernel<<<N_VOX * C_OUT / 4 / 256, 256, 0, stream>>>(out, ss);
}